// Round 14
// baseline (310.428 us; speedup 1.0000x reference)
//
#include <hip/hip_runtime.h>
#include <hip/hip_cooperative_groups.h>
#include <hip/hip_bf16.h>
#include <math.h>

namespace cg = cooperative_groups;

#define NN 10000
#define NE 160000
#define HD 128
#define NL 4
#define NG 64
#define NBLK 625            // NN/16 tiles; also NE/256 edge chunks
#define NTHR 256
#define GRIDTHREADS 160000  // NBLK*NTHR == NE exactly
#define SMEM_BYTES 19584

typedef __attribute__((ext_vector_type(8))) short bf16x8;
typedef __attribute__((ext_vector_type(4))) short bf16x4;
typedef __attribute__((ext_vector_type(4))) float f32x4;

static __device__ __forceinline__ short f2bf(float f) {
    unsigned u = __float_as_uint(f);
    unsigned r = (u + 0x7FFFu + ((u >> 16) & 1u)) >> 16;
    return (short)r;
}
static __device__ __forceinline__ float bf2f(short s) {
    return __uint_as_float(((unsigned)(unsigned short)s) << 16);
}

// ========================= shared device bodies =========================

// layer projection: hw0[n] = h[n]@W0 (bf16), hw1[n] = h[n]@W1 (fp32). 16 nodes.
__device__ __forceinline__ void pre_gemm_body(char* smem, int t, int nb,
        const float* __restrict__ h, const short* __restrict__ Wt, // [4][256][32]
        short* __restrict__ hw0, float* __restrict__ hw1) {
    short (*Ap)[136] = (short(*)[136])smem;
    {
        int nl = t >> 4, f = (t & 15) * 8;
        int n = nb + nl;
        const float* src = h + (size_t)n * HD + f;
        float4 x0 = *(const float4*)src, x1 = *(const float4*)(src + 4);
        bf16x8 pk;
        pk[0]=f2bf(x0.x); pk[1]=f2bf(x0.y); pk[2]=f2bf(x0.z); pk[3]=f2bf(x0.w);
        pk[4]=f2bf(x1.x); pk[5]=f2bf(x1.y); pk[6]=f2bf(x1.z); pk[7]=f2bf(x1.w);
        *(bf16x8*)&Ap[nl][f] = pk;
    }
    __syncthreads();
    int wave = t >> 6, lane = t & 63;
    int lx = lane & 15, kb = lane >> 4;
    f32x4 acc[4];
    #pragma unroll
    for (int j = 0; j < 4; ++j) acc[j] = (f32x4){0.f, 0.f, 0.f, 0.f};
    for (int ks = 0; ks < 4; ++ks) {
        bf16x8 a = *(const bf16x8*)&Ap[lx][ks * 32 + kb * 8];
        const short* bp = Wt + (size_t)ks * 8192 + (size_t)(wave * 64 + lx) * 32 + kb * 8;
        #pragma unroll
        for (int jj = 0; jj < 4; ++jj) {
            bf16x8 bfr = *(const bf16x8*)(bp + jj * 512);
            acc[jj] = __builtin_amdgcn_mfma_f32_16x16x32_bf16(a, bfr, acc[jj], 0, 0, 0);
        }
    }
    #pragma unroll
    for (int jj = 0; jj < 4; ++jj) {
        int c = wave * 64 + jj * 16 + lx;
        #pragma unroll
        for (int r_ = 0; r_ < 4; ++r_) {
            int n2 = nb + kb * 4 + r_;
            if (c < 128) hw0[(size_t)n2 * HD + c] = f2bf(acc[jj][r_]);
            else         hw1[(size_t)n2 * HD + (c - 128)] = acc[jj][r_];
        }
    }
}

// Fused layer: Phase A CSR-aggregate (unscaled bf16 into aggB) ->
// Phase B barrier-free GEMM with inline amp/att scaling + h_in from global ->
// C-write (bias+residual) -> optional epilogue next-layer projection.
// smem: aggB[16][3][132]@0 (12672) | btab_s[5][128]@12672 (2560) | Ap2[16][136]@15232 (4352)
__device__ __forceinline__ void fused_layer_body(char* smem, int t, int nb,
        const short* __restrict__ hw0_in, const float* __restrict__ hw1_in,
        const float* __restrict__ btabL,
        const int* __restrict__ offsets, const int* __restrict__ perm,
        const float* __restrict__ curH,
        const float* __restrict__ amp, const float* __restrict__ att,
        const short* __restrict__ Wt /* [40][128][32] */, const float* __restrict__ bias,
        float* __restrict__ nxtH,
        const short* __restrict__ nextWt, short* __restrict__ hw0o, float* __restrict__ hw1o) {
    short (*aggB)[3][132] = (short(*)[3][132])smem;
    float (*btab_s)[128]  = (float(*)[128])(smem + 12672);
    short (*Ap2)[136]     = (short(*)[136])(smem + 15232);

    if (t < 160) {
        int bb = t >> 5, f4 = (t & 31) * 4;
        *(f32x4*)&btab_s[bb][f4] = *(const f32x4*)(btabL + bb * HD + f4);
    }
    __syncthreads();

    // ---- Phase A: one thread owns (node, 8 feats); unscaled bf16 out ----
    {
        int nl = t >> 4;
        int n = nb + nl;
        int f = (t & 15) * 8;
        int s0 = offsets[n];
        int d = offsets[n + 1] - s0;
        f32x4 sum0 = {0.f,0.f,0.f,0.f}, sum1 = {0.f,0.f,0.f,0.f};
        f32x4 mx0 = {-INFINITY,-INFINITY,-INFINITY,-INFINITY};
        f32x4 mx1 = mx0;
        int i = 0;
        for (; i + 2 <= d; i += 2) {
            int p0 = perm[s0 + i], p1 = perm[s0 + i + 1];
            bf16x8 a0 = *(const bf16x8*)(hw0_in + (size_t)(p0 & 16383) * HD + f);
            bf16x8 a1 = *(const bf16x8*)(hw0_in + (size_t)(p1 & 16383) * HD + f);
            const float* t0 = &btab_s[p0 >> 14][f];
            const float* t1 = &btab_s[p1 >> 14][f];
            f32x4 b00 = *(const f32x4*)t0, b01 = *(const f32x4*)(t0 + 4);
            f32x4 b10 = *(const f32x4*)t1, b11 = *(const f32x4*)(t1 + 4);
            f32x4 v00, v01, v10, v11;
            #pragma unroll
            for (int q = 0; q < 4; ++q) {
                v00[q] = bf2f(a0[q]) + b00[q];
                v01[q] = bf2f(a0[q + 4]) + b01[q];
                v10[q] = bf2f(a1[q]) + b10[q];
                v11[q] = bf2f(a1[q + 4]) + b11[q];
            }
            sum0 += v00 + v10; sum1 += v01 + v11;
            #pragma unroll
            for (int q = 0; q < 4; ++q) {
                mx0[q] = fmaxf(mx0[q], fmaxf(v00[q], v10[q]));
                mx1[q] = fmaxf(mx1[q], fmaxf(v01[q], v11[q]));
            }
        }
        if (i < d) {
            int p0 = perm[s0 + i];
            bf16x8 a0 = *(const bf16x8*)(hw0_in + (size_t)(p0 & 16383) * HD + f);
            const float* t0 = &btab_s[p0 >> 14][f];
            f32x4 b00 = *(const f32x4*)t0, b01 = *(const f32x4*)(t0 + 4);
            f32x4 v00, v01;
            #pragma unroll
            for (int q = 0; q < 4; ++q) {
                v00[q] = bf2f(a0[q]) + b00[q];
                v01[q] = bf2f(a0[q + 4]) + b01[q];
            }
            sum0 += v00; sum1 += v01;
            #pragma unroll
            for (int q = 0; q < 4; ++q) {
                mx0[q] = fmaxf(mx0[q], v00[q]);
                mx1[q] = fmaxf(mx1[q], v01[q]);
            }
        }
        const float* cp = hw1_in + (size_t)n * HD + f;
        f32x4 c0 = *(const f32x4*)cp, c1 = *(const f32x4*)(cp + 4);
        f32x4 me0, me1, so0, so1, mo0, mo1;
        if (d > 0) {
            float df = (float)d, di = 1.f / df;
            so0 = sum0 + df * c0;  so1 = sum1 + df * c1;
            me0 = sum0 * di + c0;  me1 = sum1 * di + c1;
            mo0 = mx0 + c0;        mo1 = mx1 + c1;
        } else {
            me0 = (f32x4){0.f,0.f,0.f,0.f}; me1 = me0;
            so0 = me0; so1 = me0; mo0 = me0; mo1 = me0;
        }
        bf16x8 pk;
        #pragma unroll
        for (int q = 0; q < 4; ++q) { pk[q] = f2bf(me0[q]); pk[q+4] = f2bf(me1[q]); }
        *(bf16x8*)&aggB[nl][0][f] = pk;
        #pragma unroll
        for (int q = 0; q < 4; ++q) { pk[q] = f2bf(so0[q]); pk[q+4] = f2bf(so1[q]); }
        *(bf16x8*)&aggB[nl][1][f] = pk;
        #pragma unroll
        for (int q = 0; q < 4; ++q) { pk[q] = f2bf(mo0[q]); pk[q+4] = f2bf(mo1[q]); }
        *(bf16x8*)&aggB[nl][2][f] = pk;
    }
    __syncthreads();

    // ---- Phase B: barrier-free GEMM; wave w owns cols [w*32, w*32+32) ----
    int wave = t >> 6, lane = t & 63;
    int lx = lane & 15, kb = lane >> 4;
    int n_lx = nb + lx;
    float famp = amp[n_lx], fatt = att[n_lx];
    f32x4 acc0 = {0.f,0.f,0.f,0.f}, acc1 = acc0;
    for (int ks = 0; ks < 40; ++ks) {
        int r = ks >> 2;
        int kk = (ks & 3) * 32 + kb * 8;
        bf16x8 afrag;
        if (r < 9) {
            int ag = r % 3, fi = r / 3;
            bf16x8 raw = *(const bf16x8*)&aggB[lx][ag][kk];
            if (fi == 0) afrag = raw;
            else {
                float fac = (fi == 1) ? famp : fatt;
                #pragma unroll
                for (int q = 0; q < 8; ++q) afrag[q] = f2bf(bf2f(raw[q]) * fac);
            }
        } else {
            const float* src = curH + (size_t)n_lx * HD + kk;
            float4 x0 = *(const float4*)src, x1 = *(const float4*)(src + 4);
            afrag[0]=f2bf(x0.x); afrag[1]=f2bf(x0.y); afrag[2]=f2bf(x0.z); afrag[3]=f2bf(x0.w);
            afrag[4]=f2bf(x1.x); afrag[5]=f2bf(x1.y); afrag[6]=f2bf(x1.z); afrag[7]=f2bf(x1.w);
        }
        const short* bp = Wt + (size_t)ks * 4096 + (size_t)(wave * 32 + lx) * 32 + kb * 8;
        bf16x8 b0 = *(const bf16x8*)bp;
        bf16x8 b1 = *(const bf16x8*)(bp + 512);
        acc0 = __builtin_amdgcn_mfma_f32_16x16x32_bf16(afrag, b0, acc0, 0, 0, 0);
        acc1 = __builtin_amdgcn_mfma_f32_16x16x32_bf16(afrag, b1, acc1, 0, 0, 0);
    }
    #pragma unroll
    for (int jj = 0; jj < 2; ++jj) {
        int c = wave * 32 + jj * 16 + lx;
        float bc = bias[c];
        f32x4 av = jj ? acc1 : acc0;
        #pragma unroll
        for (int r_ = 0; r_ < 4; ++r_) {
            int n2 = nb + kb * 4 + r_;
            size_t off = (size_t)n2 * HD + c;
            float ho = av[r_] + bc + curH[off];
            nxtH[off] = ho;
            Ap2[n2 - nb][c] = f2bf(ho);
        }
    }
    if (nextWt != nullptr) {
        __syncthreads();
        f32x4 acc[4];
        #pragma unroll
        for (int j = 0; j < 4; ++j) acc[j] = (f32x4){0.f, 0.f, 0.f, 0.f};
        for (int ks = 0; ks < 4; ++ks) {
            bf16x8 aa = *(const bf16x8*)&Ap2[lx][ks * 32 + kb * 8];
            const short* bp = nextWt + (size_t)ks * 8192 + (size_t)(wave * 64 + lx) * 32 + kb * 8;
            #pragma unroll
            for (int jj = 0; jj < 4; ++jj) {
                bf16x8 bfr = *(const bf16x8*)(bp + jj * 512);
                acc[jj] = __builtin_amdgcn_mfma_f32_16x16x32_bf16(aa, bfr, acc[jj], 0, 0, 0);
            }
        }
        #pragma unroll
        for (int jj = 0; jj < 4; ++jj) {
            int c = wave * 64 + jj * 16 + lx;
            #pragma unroll
            for (int r_ = 0; r_ < 4; ++r_) {
                int n2 = nb + kb * 4 + r_;
                if (c < 128) hw0o[(size_t)n2 * HD + c] = f2bf(acc[jj][r_]);
                else         hw1o[(size_t)n2 * HD + (c - 128)] = acc[jj][r_];
            }
        }
    }
}

// graph pooling + output MLP for graph g (batch sorted). smem >= 3584B.
__device__ __forceinline__ void pool_body(char* smem, int t, int g,
        const float* __restrict__ h, const int* __restrict__ batch,
        const float* __restrict__ W1, const float* __restrict__ b1,
        const float* __restrict__ W2, const float* __restrict__ b2,
        float* __restrict__ out) {
    float* rs  = (float*)smem;          // 384
    float* red = rs + 384;              // 256
    float* s2  = red + 256;             // 128
    float* m2  = s2 + 128;              // 128
    int lo = 0, hi = NN;
    while (lo < hi) { int mid = (lo + hi) >> 1; if (batch[mid] < g) lo = mid + 1; else hi = mid; }
    int lo2 = lo, hi2 = NN;
    while (lo2 < hi2) { int mid = (lo2 + hi2) >> 1; if (batch[mid] < g + 1) lo2 = mid + 1; else hi2 = mid; }
    int cnt = lo2 - lo;
    int f = t & 127, grp = t >> 7;
    float sum = 0.f, mx = -INFINITY;
    for (int n = lo + grp; n < lo2; n += 2) {
        float v = h[(size_t)n * HD + f];
        sum += v; mx = fmaxf(mx, v);
    }
    if (grp == 1) { s2[f] = sum; m2[f] = mx; }
    __syncthreads();
    if (grp == 0) {
        sum += s2[f]; mx = fmaxf(mx, m2[f]);
        float mean = (cnt > 0) ? sum / (float)cnt : 0.f;
        float so = (cnt > 0) ? sum : 0.f;
        float mo = (cnt > 0) ? mx : 0.f;
        if (isnan(mean) || isinf(mean)) mean = 0.f;
        if (isnan(so) || isinf(so)) so = 0.f;
        if (isnan(mo) || isinf(mo)) mo = 0.f;
        rs[f] = mean; rs[128 + f] = so; rs[256 + f] = mo;
    }
    __syncthreads();
    {
        int j = t & 127, kh = t >> 7;
        float acc = 0.f;
        for (int k = kh * 192; k < kh * 192 + 192; ++k)
            acc = fmaf(rs[k], W1[k * HD + j], acc);
        red[t] = acc;
    }
    __syncthreads();
    if (t < 128) {
        float v = fmaxf(red[t] + red[128 + t] + b1[t], 0.f);
        red[t] = v * W2[t];
    }
    __syncthreads();
    for (int s = 64; s > 0; s >>= 1) {
        if (t < s) red[t] += red[t + s];
        __syncthreads();
    }
    if (t == 0) {
        float o = red[0] + b2[0];
        if (isnan(o) || isinf(o)) o = 0.f;
        out[g] = o;
    }
}

// ========================= fallback kernels =========================

__global__ void setup1_kernel(const int* __restrict__ x, const float* __restrict__ atom_emb,
                              float* __restrict__ h, float* __restrict__ deg,
                              int* __restrict__ cursor) {
    int idx = blockIdx.x * 256 + threadIdx.x;
    if (idx < NN) { deg[idx] = 0.f; cursor[idx] = 0; }
    if (idx < NN * HD) {
        int n = idx >> 7, f = idx & 127;
        h[idx] = atom_emb[x[n] * HD + f];
    }
}

__global__ __launch_bounds__(256) void setup2_kernel(
    const int* __restrict__ col, float* __restrict__ deg,
    const float* __restrict__ bond_emb,
    const float* __restrict__ pre_W, const float* __restrict__ pre_b,
    const float* __restrict__ post_W,
    float* __restrict__ btab, short* __restrict__ pre_Wt, short* __restrict__ post_Wt) {
    int b = blockIdx.x;
    if (b < 625) {
        int e = b * 256 + threadIdx.x;
        if (e < NE) atomicAdd(&deg[col[e]], 1.f);
        return;
    }
    if (b < 645) {
        int lb = b - 625;
        if (threadIdx.x < 128) {
            int l = lb / 5, bb = lb % 5;
            int f = threadIdx.x;
            const float* W2 = pre_W + (size_t)l * 384 * HD + 256 * HD;
            const float* eb = bond_emb + bb * HD;
            float acc = pre_b[l * HD + f];
            for (int k = 0; k < HD; ++k) acc = fmaf(eb[k], W2[k * HD + f], acc);
            btab[(l * 5 + bb) * HD + f] = acc;
        }
        return;
    }
    int idx = (b - 645) * 256 + threadIdx.x;
    if (idx < NL * 4 * 256 * 32) {
        int l = idx >> 15;
        int r = idx & 32767;
        int kblk = r >> 13;
        int rr = r & 8191;
        int j = rr >> 5, k = rr & 31;
        const float* Wl = pre_W + (size_t)l * 384 * HD;
        float v = (j < 128) ? Wl[(kblk * 32 + k) * HD + j]
                            : Wl[(128 + kblk * 32 + k) * HD + (j - 128)];
        pre_Wt[idx] = f2bf(v);
    }
    if (idx < NL * 40 * 128 * 32) {
        int l = idx / 163840;
        int r = idx % 163840;
        int kblk = r >> 12;
        int rr = r & 4095;
        int j = rr >> 5, k = rr & 31;
        post_Wt[idx] = f2bf(post_W[(size_t)l * 163840 + (size_t)(kblk * 32 + k) * HD + j]);
    }
}

__global__ __launch_bounds__(1024) void scan_facs_kernel(const float* __restrict__ deg,
                                                         int* __restrict__ offsets,
                                                         float* __restrict__ amp,
                                                         float* __restrict__ att) {
    __shared__ int s[1024];
    int t = threadIdx.x;
    int base = t * 10;
    int v[10];
    int lsum = 0;
    #pragma unroll
    for (int i = 0; i < 10; ++i) {
        int idx = base + i;
        int d = (idx < NN) ? (int)deg[idx] : 0;
        v[i] = d;
        lsum += d;
        if (idx < NN) {
            float logD = logf((float)d + 1.f);
            amp[idx] = logD;
            att[idx] = 1.f / fmaxf(logD, 1e-8f);
        }
    }
    s[t] = lsum;
    __syncthreads();
    for (int off = 1; off < 1024; off <<= 1) {
        int x2 = (t >= off) ? s[t - off] : 0;
        __syncthreads();
        s[t] += x2;
        __syncthreads();
    }
    int run = s[t] - lsum;
    #pragma unroll
    for (int i = 0; i < 10; ++i) {
        int idx = base + i;
        if (idx < NN) offsets[idx] = run;
        run += v[i];
    }
    if (t == 1023) offsets[NN] = run;
}

__global__ void scatter_kernel(const int* __restrict__ row, const int* __restrict__ col,
                               const int* __restrict__ ea, const int* __restrict__ offsets,
                               int* __restrict__ cursor, int* __restrict__ perm) {
    int e = blockIdx.x * 256 + threadIdx.x;
    if (e < NE) {
        int c = col[e];
        int pos = offsets[c] + atomicAdd(&cursor[c], 1);
        perm[pos] = row[e] | (ea[e] << 14);
    }
}

__global__ __launch_bounds__(256, 4) void pre_gemm_kernel(const float* __restrict__ h,
                                                          const short* __restrict__ Wt,
                                                          short* __restrict__ hw0,
                                                          float* __restrict__ hw1) {
    __shared__ __align__(16) char smem[4352];
    pre_gemm_body(smem, threadIdx.x, blockIdx.x * 16, h, Wt, hw0, hw1);
}

__global__ __launch_bounds__(256, 4) void fused_kernel(
    const short* hw0_in, const float* hw1_in, const float* btabL,
    const int* offsets, const int* perm, const float* curH,
    const float* amp, const float* att,
    const short* Wt, const float* bias, float* nxtH,
    const short* nextWt, short* hw0o, float* hw1o) {
    __shared__ __align__(16) char smem[SMEM_BYTES];
    fused_layer_body(smem, threadIdx.x, blockIdx.x * 16, hw0_in, hw1_in, btabL,
                     offsets, perm, curH, amp, att, Wt, bias, nxtH, nextWt, hw0o, hw1o);
}

__global__ __launch_bounds__(256) void pool_out_kernel(
    const float* h, const int* batch,
    const float* W1, const float* b1, const float* W2, const float* b2,
    float* out) {
    __shared__ __align__(16) char smem[3584];
    pool_body(smem, threadIdx.x, blockIdx.x, h, batch, W1, b1, W2, b2, out);
}

// ========================= cooperative mega kernel =========================

struct MegaArgs {
    const int* x; const int* row; const int* col; const int* ea; const int* batch;
    const float* atom_emb; const float* bond_emb;
    const float* pre_W; const float* pre_b; const float* post_W; const float* post_b;
    const float* out_W1; const float* out_b1; const float* out_W2; const float* out_b2;
    float* out;
    float* deg; float* amp; float* att; int* offsets; int* cursor; int* perm;
    float* hA; float* hB; short* hw0A; short* hw0B; float* hw1A; float* hw1B;
    float* btab; short* pre_Wt; short* post_Wt;
};

__global__ __launch_bounds__(256, 4) void mega_kernel(MegaArgs a) {
    cg::grid_group grid = cg::this_grid();
    __shared__ __align__(16) char smem[SMEM_BYTES];
    int t = threadIdx.x, b = blockIdx.x;
    int gid = b * NTHR + t;
    int nb = b * 16;

    // P0: embed + clears + weight conversion + btab
    #pragma unroll
    for (int i = 0; i < 8; ++i) {
        int idx = gid + i * GRIDTHREADS;
        int n = idx >> 7, f = idx & 127;
        a.hA[idx] = a.atom_emb[a.x[n] * HD + f];
    }
    if (gid < NN) { a.deg[gid] = 0.f; a.cursor[gid] = 0; }
    if (gid < NL * 4 * 256 * 32) {
        int idx = gid;
        int l = idx >> 15;
        int r = idx & 32767;
        int kblk = r >> 13;
        int rr = r & 8191;
        int j = rr >> 5, k = rr & 31;
        const float* Wl = a.pre_W + (size_t)l * 384 * HD;
        float v = (j < 128) ? Wl[(kblk * 32 + k) * HD + j]
                            : Wl[(128 + kblk * 32 + k) * HD + (j - 128)];
        a.pre_Wt[idx] = f2bf(v);
    }
    for (int idx = gid; idx < NL * 40 * 128 * 32; idx += GRIDTHREADS) {
        int l = idx / 163840;
        int r = idx % 163840;
        int kblk = r >> 12;
        int rr = r & 4095;
        int j = rr >> 5, k = rr & 31;
        a.post_Wt[idx] = f2bf(a.post_W[(size_t)l * 163840 + (size_t)(kblk * 32 + k) * HD + j]);
    }
    if (b < 20 && t < 128) {
        int l = b / 5, bb = b % 5;
        const float* W2 = a.pre_W + (size_t)l * 384 * HD + 256 * HD;
        const float* eb = a.bond_emb + bb * HD;
        float acc = a.pre_b[l * HD + t];
        for (int k = 0; k < HD; ++k) acc = fmaf(eb[k], W2[k * HD + t], acc);
        a.btab[(l * 5 + bb) * HD + t] = acc;
    }
    grid.sync();

    // P1: degree histogram (one edge per thread)
    atomicAdd(&a.deg[a.col[gid]], 1.f);
    grid.sync();

    // P2: amp/att (all) + offsets scan (block 0, 256 thr x 40 elems)
    if (gid < NN) {
        float logD = logf(a.deg[gid] + 1.f);
        a.amp[gid] = logD;
        a.att[gid] = 1.f / fmaxf(logD, 1e-8f);
    }
    if (b == 0) {
        int* ssc = (int*)smem;
        int lsum = 0;
        for (int i = 0; i < 40; ++i) {
            int idx = t * 40 + i;
            lsum += (idx < NN) ? (int)a.deg[idx] : 0;
        }
        ssc[t] = lsum;
        __syncthreads();
        for (int off = 1; off < 256; off <<= 1) {
            int x2 = (t >= off) ? ssc[t - off] : 0;
            __syncthreads();
            ssc[t] += x2;
            __syncthreads();
        }
        int run = ssc[t] - lsum;
        for (int i = 0; i < 40; ++i) {
            int idx = t * 40 + i;
            if (idx < NN) { a.offsets[idx] = run; run += (int)a.deg[idx]; }
        }
        if (t == 255) a.offsets[NN] = run;
    }
    grid.sync();

    // P3: scatter edges into CSR
    {
        int c = a.col[gid];
        int pos = a.offsets[c] + atomicAdd(&a.cursor[c], 1);
        a.perm[pos] = a.row[gid] | (a.ea[gid] << 14);
    }
    grid.sync();

    // P4: layer-0 projection
    pre_gemm_body(smem, t, nb, a.hA, a.pre_Wt, a.hw0A, a.hw1A);
    grid.sync();

    // P5: 4 fused layers
    float* curH = a.hA;
    float* nxtH = a.hB;
    const short* hw0_in = a.hw0A;
    const float* hw1_in = a.hw1A;
    for (int l = 0; l < NL; ++l) {
        short* hw0_out = (l & 1) ? a.hw0A : a.hw0B;
        float* hw1_out = (l & 1) ? a.hw1A : a.hw1B;
        const short* nextWt = (l + 1 < NL) ? (a.pre_Wt + (size_t)(l + 1) * 32768) : nullptr;
        fused_layer_body(smem, t, nb, hw0_in, hw1_in, a.btab + (size_t)l * 5 * HD,
                         a.offsets, a.perm, curH, a.amp, a.att,
                         a.post_Wt + (size_t)l * 163840, a.post_b + (size_t)l * HD,
                         nxtH, nextWt, hw0_out, hw1_out);
        float* tmp = curH; curH = nxtH; nxtH = tmp;
        hw0_in = hw0_out; hw1_in = hw1_out;
        grid.sync();
    }

    // P6: pooled output MLP (blocks 0..63)
    if (b < NG) {
        pool_body(smem, t, b, curH, a.batch, a.out_W1, a.out_b1, a.out_W2, a.out_b2, a.out);
    }
}

// ========================= host launcher =========================

extern "C" void kernel_launch(void* const* d_in, const int* in_sizes, int n_in,
                              void* d_out, int out_size, void* d_ws, size_t ws_size,
                              hipStream_t stream)
{
    const int* x          = (const int*)d_in[0];
    const int* ei         = (const int*)d_in[1];
    const int* ea         = (const int*)d_in[2];
    const int* batch      = (const int*)d_in[3];
    const float* atom_emb = (const float*)d_in[4];
    const float* bond_emb = (const float*)d_in[5];
    const float* pre_W    = (const float*)d_in[6];
    const float* pre_b    = (const float*)d_in[7];
    const float* post_W   = (const float*)d_in[8];
    const float* post_b   = (const float*)d_in[9];
    const float* out_W1   = (const float*)d_in[10];
    const float* out_b1   = (const float*)d_in[11];
    const float* out_W2   = (const float*)d_in[12];
    const float* out_b2   = (const float*)d_in[13];
    float* out = (float*)d_out;
    const int* row = ei;
    const int* col = ei + NE;

    char* p = (char*)d_ws;
    auto alloc = [&](size_t bytes) { char* r = p; p += (bytes + 255) & ~(size_t)255; return r; };
    float*    deg     = (float*)alloc((size_t)NN * 4);
    float*    amp     = (float*)alloc((size_t)NN * 4);
    float*    att     = (float*)alloc((size_t)NN * 4);
    int*      offsets = (int*)alloc((size_t)(NN + 1) * 4);
    int*      cursor  = (int*)alloc((size_t)NN * 4);
    int*      perm    = (int*)alloc((size_t)NE * 4);
    float*    hA      = (float*)alloc((size_t)NN * HD * 4);
    float*    hB      = (float*)alloc((size_t)NN * HD * 4);
    short*    hw0A    = (short*)alloc((size_t)NN * HD * 2);
    short*    hw0B    = (short*)alloc((size_t)NN * HD * 2);
    float*    hw1A    = (float*)alloc((size_t)NN * HD * 4);
    float*    hw1B    = (float*)alloc((size_t)NN * HD * 4);
    float*    btab    = (float*)alloc((size_t)NL * 5 * HD * 4);
    short*    pre_Wt  = (short*)alloc((size_t)NL * 4 * 256 * 32 * 2);
    short*    post_Wt = (short*)alloc((size_t)NL * 40 * 128 * 32 * 2);

    // Deterministic capacity pre-check for the cooperative launch (capture-safe queries).
    int occ = 0;
    hipError_t oerr = hipOccupancyMaxActiveBlocksPerMultiprocessor(&occ, mega_kernel, NTHR, 0);
    int dev = 0, numCU = 0;
    hipGetDevice(&dev);
    hipDeviceGetAttribute(&numCU, hipDeviceAttributeMultiprocessorCount, dev);
    bool use_coop = (oerr == hipSuccess) && (occ > 0) && ((long)occ * (long)numCU >= NBLK);

    if (use_coop) {
        MegaArgs ma;
        ma.x = x; ma.row = row; ma.col = col; ma.ea = ea; ma.batch = batch;
        ma.atom_emb = atom_emb; ma.bond_emb = bond_emb;
        ma.pre_W = pre_W; ma.pre_b = pre_b; ma.post_W = post_W; ma.post_b = post_b;
        ma.out_W1 = out_W1; ma.out_b1 = out_b1; ma.out_W2 = out_W2; ma.out_b2 = out_b2;
        ma.out = out;
        ma.deg = deg; ma.amp = amp; ma.att = att; ma.offsets = offsets; ma.cursor = cursor;
        ma.perm = perm; ma.hA = hA; ma.hB = hB;
        ma.hw0A = hw0A; ma.hw0B = hw0B; ma.hw1A = hw1A; ma.hw1B = hw1B;
        ma.btab = btab; ma.pre_Wt = pre_Wt; ma.post_Wt = post_Wt;
        void* kargs[] = { (void*)&ma };
        hipLaunchCooperativeKernel((const void*)mega_kernel, dim3(NBLK), dim3(NTHR),
                                   kargs, 0, stream);
        return;
    }

    // Fallback: proven multi-kernel sequence (same math).
    setup1_kernel<<<(NN * HD) / 256, 256, 0, stream>>>(x, atom_emb, hA, deg, cursor);
    setup2_kernel<<<645 + (NL * 40 * 128 * 32 + 255) / 256, 256, 0, stream>>>(
        col, deg, bond_emb, pre_W, pre_b, post_W, btab, pre_Wt, post_Wt);
    scan_facs_kernel<<<1, 1024, 0, stream>>>(deg, offsets, amp, att);
    scatter_kernel<<<(NE + 255) / 256, 256, 0, stream>>>(row, col, ea, offsets, cursor, perm);
    pre_gemm_kernel<<<NBLK, 256, 0, stream>>>(hA, pre_Wt, hw0A, hw1A);

    float* curH = hA;
    float* nxtH = hB;
    const short* hw0_in = hw0A;
    const float* hw1_in = hw1A;
    for (int l = 0; l < NL; ++l) {
        short* hw0_out = (l & 1) ? hw0A : hw0B;
        float* hw1_out = (l & 1) ? hw1A : hw1B;
        const short* nextWt = (l + 1 < NL) ? (pre_Wt + (size_t)(l + 1) * 32768) : nullptr;
        fused_kernel<<<NBLK, 256, 0, stream>>>(
            hw0_in, hw1_in, btab + (size_t)l * 5 * HD, offsets, perm,
            curH, amp, att, post_Wt + (size_t)l * 163840,
            post_b + (size_t)l * HD, nxtH, nextWt, hw0_out, hw1_out);
        float* tmp = curH; curH = nxtH; nxtH = tmp;
        hw0_in = hw0_out; hw1_in = hw1_out;
    }

    pool_out_kernel<<<NG, 256, 0, stream>>>(curH, batch, out_W1, out_b1, out_W2, out_b2, out);
}

// Round 15
// 288.611 us; speedup vs baseline: 1.0756x; 1.0756x over previous
//
#include <hip/hip_runtime.h>
#include <hip/hip_bf16.h>
#include <math.h>

#define NN 10000
#define NE 160000
#define HD 128
#define NL 4
#define NG 64
#define NBLK 625            // NN/16 tiles
#define SMEM_BYTES 19584

typedef __attribute__((ext_vector_type(8))) short bf16x8;
typedef __attribute__((ext_vector_type(4))) short bf16x4;
typedef __attribute__((ext_vector_type(4))) float f32x4;

static __device__ __forceinline__ short f2bf(float f) {
    unsigned u = __float_as_uint(f);
    unsigned r = (u + 0x7FFFu + ((u >> 16) & 1u)) >> 16;
    return (short)r;
}
static __device__ __forceinline__ float bf2f(short s) {
    return __uint_as_float(((unsigned)(unsigned short)s) << 16);
}

// setup1: embed h + clear deg/cursor
__global__ void setup1_kernel(const int* __restrict__ x, const float* __restrict__ atom_emb,
                              float* __restrict__ h, float* __restrict__ deg,
                              int* __restrict__ cursor) {
    int idx = blockIdx.x * 256 + threadIdx.x;
    if (idx < NN) { deg[idx] = 0.f; cursor[idx] = 0; }
    if (idx < NN * HD) {
        int n = idx >> 7, f = idx & 127;
        h[idx] = atom_emb[x[n] * HD + f];
    }
}

// setup2: blocks [0,625): deg histogram; [625,645): btab; rest: weight conversion.
//   pre_Wt[l][kblk<4][j<256][k<32], post_Wt[l][kblk<40][j<128][k<32]
__global__ __launch_bounds__(256) void setup2_kernel(
    const int* __restrict__ col, float* __restrict__ deg,
    const float* __restrict__ bond_emb,
    const float* __restrict__ pre_W, const float* __restrict__ pre_b,
    const float* __restrict__ post_W,
    float* __restrict__ btab, short* __restrict__ pre_Wt, short* __restrict__ post_Wt) {
    int b = blockIdx.x;
    if (b < 625) {
        int e = b * 256 + threadIdx.x;
        if (e < NE) atomicAdd(&deg[col[e]], 1.f);
        return;
    }
    if (b < 645) {
        int lb = b - 625;
        if (threadIdx.x < 128) {
            int l = lb / 5, bb = lb % 5;
            int f = threadIdx.x;
            const float* W2 = pre_W + (size_t)l * 384 * HD + 256 * HD;
            const float* eb = bond_emb + bb * HD;
            float acc = pre_b[l * HD + f];
            for (int k = 0; k < HD; ++k) acc = fmaf(eb[k], W2[k * HD + f], acc);
            btab[(l * 5 + bb) * HD + f] = acc;
        }
        return;
    }
    int idx = (b - 645) * 256 + threadIdx.x;
    if (idx < NL * 4 * 256 * 32) {      // 131072
        int l = idx >> 15;
        int r = idx & 32767;
        int kblk = r >> 13;
        int rr = r & 8191;
        int j = rr >> 5, k = rr & 31;
        const float* Wl = pre_W + (size_t)l * 384 * HD;
        float v = (j < 128) ? Wl[(kblk * 32 + k) * HD + j]
                            : Wl[(128 + kblk * 32 + k) * HD + (j - 128)];
        pre_Wt[idx] = f2bf(v);
    }
    if (idx < NL * 40 * 128 * 32) {     // 655360
        int l = idx / 163840;
        int r = idx % 163840;
        int kblk = r >> 12;
        int rr = r & 4095;
        int j = rr >> 5, k = rr & 31;
        post_Wt[idx] = f2bf(post_W[(size_t)l * 163840 + (size_t)(kblk * 32 + k) * HD + j]);
    }
}

// One-pass parallel exclusive scan (1024 thr x 10 elems) + amp/att factors.
__global__ __launch_bounds__(1024) void scan_facs_kernel(const float* __restrict__ deg,
                                                         int* __restrict__ offsets,
                                                         float* __restrict__ amp,
                                                         float* __restrict__ att) {
    __shared__ int s[1024];
    int t = threadIdx.x;
    int base = t * 10;
    int v[10];
    int lsum = 0;
    #pragma unroll
    for (int i = 0; i < 10; ++i) {
        int idx = base + i;
        int d = (idx < NN) ? (int)deg[idx] : 0;
        v[i] = d;
        lsum += d;
        if (idx < NN) {
            float logD = logf((float)d + 1.f);
            amp[idx] = logD;                       // / AVG_D_LOG (=1.0)
            att[idx] = 1.f / fmaxf(logD, 1e-8f);   // AVG_D_LOG / max(logD, eps)
        }
    }
    s[t] = lsum;
    __syncthreads();
    for (int off = 1; off < 1024; off <<= 1) {
        int x2 = (t >= off) ? s[t - off] : 0;
        __syncthreads();
        s[t] += x2;
        __syncthreads();
    }
    int run = s[t] - lsum;
    #pragma unroll
    for (int i = 0; i < 10; ++i) {
        int idx = base + i;
        if (idx < NN) offsets[idx] = run;
        run += v[i];
    }
    if (t == 1023) offsets[NN] = run;   // = NE
}

__global__ void scatter_kernel(const int* __restrict__ row, const int* __restrict__ col,
                               const int* __restrict__ ea, const int* __restrict__ offsets,
                               int* __restrict__ cursor, int* __restrict__ perm) {
    int e = blockIdx.x * 256 + threadIdx.x;
    if (e < NE) {
        int c = col[e];
        int pos = offsets[c] + atomicAdd(&cursor[c], 1);
        perm[pos] = row[e] | (ea[e] << 14);   // row < 16384, ea < 5
    }
}

// Layer-0 projection: hw0[n] = h[n]@W0 (bf16), hw1[n] = h[n]@W1 (fp32). 16 nodes/block.
__global__ __launch_bounds__(256, 4) void pre_gemm_kernel(const float* __restrict__ h,
                                                          const short* __restrict__ Wt, // [4][256][32]
                                                          short* __restrict__ hw0,
                                                          float* __restrict__ hw1) {
    __shared__ short Ap[16][136];
    int t = threadIdx.x;
    int nb = blockIdx.x * 16;
    {
        int nl = t >> 4, f = (t & 15) * 8;
        int n = nb + nl;
        const float* src = h + (size_t)n * HD + f;
        float4 x0 = *(const float4*)src, x1 = *(const float4*)(src + 4);
        bf16x8 pk;
        pk[0]=f2bf(x0.x); pk[1]=f2bf(x0.y); pk[2]=f2bf(x0.z); pk[3]=f2bf(x0.w);
        pk[4]=f2bf(x1.x); pk[5]=f2bf(x1.y); pk[6]=f2bf(x1.z); pk[7]=f2bf(x1.w);
        *(bf16x8*)&Ap[nl][f] = pk;
    }
    __syncthreads();
    int wave = t >> 6, lane = t & 63;
    int lx = lane & 15, kb = lane >> 4;
    f32x4 acc[4];
    #pragma unroll
    for (int j = 0; j < 4; ++j) acc[j] = (f32x4){0.f, 0.f, 0.f, 0.f};
    #pragma unroll
    for (int ks = 0; ks < 4; ++ks) {
        bf16x8 a = *(const bf16x8*)&Ap[lx][ks * 32 + kb * 8];
        const short* bp = Wt + (size_t)ks * 8192 + (size_t)(wave * 64 + lx) * 32 + kb * 8;
        #pragma unroll
        for (int jj = 0; jj < 4; ++jj) {
            bf16x8 bfr = *(const bf16x8*)(bp + jj * 512);
            acc[jj] = __builtin_amdgcn_mfma_f32_16x16x32_bf16(a, bfr, acc[jj], 0, 0, 0);
        }
    }
    #pragma unroll
    for (int jj = 0; jj < 4; ++jj) {
        int c = wave * 64 + jj * 16 + lx;
        #pragma unroll
        for (int r_ = 0; r_ < 4; ++r_) {
            int n2 = nb + kb * 4 + r_;
            if (c < 128) hw0[(size_t)n2 * HD + c] = f2bf(acc[jj][r_]);
            else         hw1[(size_t)n2 * HD + (c - 128)] = acc[jj][r_];
        }
    }
}

// FUSED layer: Phase A CSR-aggregate (4-deep unroll, unscaled bf16 into aggB) ->
// Phase B fully-unrolled barrier-free GEMM (inline amp/att scaling; B pipelined from L2) ->
// C-write (bias+residual) -> optional epilogue next-layer projection.
// smem: aggB[16][3][132]@0 (12672) | btab_s[5][128]@12672 (2560) | Ap2[16][136]@15232 (4352)
__global__ __launch_bounds__(256, 4) void fused_kernel(
    const short* __restrict__ hw0_in, const float* __restrict__ hw1_in,
    const float* __restrict__ btabL,
    const int* __restrict__ offsets, const int* __restrict__ perm,
    const float* __restrict__ curH,
    const float* __restrict__ amp, const float* __restrict__ att,
    const short* __restrict__ Wt /* [40][128][32] */, const float* __restrict__ bias,
    float* __restrict__ nxtH,
    const short* __restrict__ nextWt, short* __restrict__ hw0o, float* __restrict__ hw1o) {
    __shared__ __align__(16) char smem[SMEM_BYTES];
    short (*aggB)[3][132] = (short(*)[3][132])smem;
    float (*btab_s)[128]  = (float(*)[128])(smem + 12672);
    short (*Ap2)[136]     = (short(*)[136])(smem + 15232);
    int t = threadIdx.x;
    int nb = blockIdx.x * 16;

    if (t < 160) {
        int bb = t >> 5, f4 = (t & 31) * 4;
        *(f32x4*)&btab_s[bb][f4] = *(const f32x4*)(btabL + bb * HD + f4);
    }
    __syncthreads();

    // ---- Phase A: one thread owns (node, 8 feats); 4 edges in flight ----
    {
        int nl = t >> 4;
        int n = nb + nl;
        int f = (t & 15) * 8;
        int s0 = offsets[n];
        int d = offsets[n + 1] - s0;
        f32x4 sum0 = {0.f,0.f,0.f,0.f}, sum1 = {0.f,0.f,0.f,0.f};
        f32x4 mx0 = {-INFINITY,-INFINITY,-INFINITY,-INFINITY};
        f32x4 mx1 = mx0;
        int i = 0;
        for (; i + 4 <= d; i += 4) {
            int p0 = perm[s0 + i],     p1 = perm[s0 + i + 1];
            int p2 = perm[s0 + i + 2], p3 = perm[s0 + i + 3];
            bf16x8 a0 = *(const bf16x8*)(hw0_in + (size_t)(p0 & 16383) * HD + f);
            bf16x8 a1 = *(const bf16x8*)(hw0_in + (size_t)(p1 & 16383) * HD + f);
            bf16x8 a2 = *(const bf16x8*)(hw0_in + (size_t)(p2 & 16383) * HD + f);
            bf16x8 a3 = *(const bf16x8*)(hw0_in + (size_t)(p3 & 16383) * HD + f);
            const float* t0 = &btab_s[p0 >> 14][f];
            const float* t1 = &btab_s[p1 >> 14][f];
            const float* t2 = &btab_s[p2 >> 14][f];
            const float* t3 = &btab_s[p3 >> 14][f];
            #pragma unroll
            for (int q = 0; q < 4; ++q) {
                float v00 = bf2f(a0[q]) + t0[q];
                float v01 = bf2f(a0[q+4]) + t0[q+4];
                float v10 = bf2f(a1[q]) + t1[q];
                float v11 = bf2f(a1[q+4]) + t1[q+4];
                float v20 = bf2f(a2[q]) + t2[q];
                float v21 = bf2f(a2[q+4]) + t2[q+4];
                float v30 = bf2f(a3[q]) + t3[q];
                float v31 = bf2f(a3[q+4]) + t3[q+4];
                sum0[q] += (v00 + v10) + (v20 + v30);
                sum1[q] += (v01 + v11) + (v21 + v31);
                mx0[q] = fmaxf(fmaxf(fmaxf(mx0[q], v00), fmaxf(v10, v20)), v30);
                mx1[q] = fmaxf(fmaxf(fmaxf(mx1[q], v01), fmaxf(v11, v21)), v31);
            }
        }
        for (; i < d; ++i) {
            int p0 = perm[s0 + i];
            bf16x8 a0 = *(const bf16x8*)(hw0_in + (size_t)(p0 & 16383) * HD + f);
            const float* t0 = &btab_s[p0 >> 14][f];
            #pragma unroll
            for (int q = 0; q < 4; ++q) {
                float v00 = bf2f(a0[q]) + t0[q];
                float v01 = bf2f(a0[q+4]) + t0[q+4];
                sum0[q] += v00; sum1[q] += v01;
                mx0[q] = fmaxf(mx0[q], v00);
                mx1[q] = fmaxf(mx1[q], v01);
            }
        }
        const float* cp = hw1_in + (size_t)n * HD + f;
        f32x4 c0 = *(const f32x4*)cp, c1 = *(const f32x4*)(cp + 4);
        f32x4 me0, me1, so0, so1, mo0, mo1;
        if (d > 0) {
            float df = (float)d, di = 1.f / df;
            so0 = sum0 + df * c0;  so1 = sum1 + df * c1;
            me0 = sum0 * di + c0;  me1 = sum1 * di + c1;
            mo0 = mx0 + c0;        mo1 = mx1 + c1;
        } else {
            me0 = (f32x4){0.f,0.f,0.f,0.f}; me1 = me0;
            so0 = me0; so1 = me0; mo0 = me0; mo1 = me0;
        }
        bf16x8 pk;
        #pragma unroll
        for (int q = 0; q < 4; ++q) { pk[q] = f2bf(me0[q]); pk[q+4] = f2bf(me1[q]); }
        *(bf16x8*)&aggB[nl][0][f] = pk;
        #pragma unroll
        for (int q = 0; q < 4; ++q) { pk[q] = f2bf(so0[q]); pk[q+4] = f2bf(so1[q]); }
        *(bf16x8*)&aggB[nl][1][f] = pk;
        #pragma unroll
        for (int q = 0; q < 4; ++q) { pk[q] = f2bf(mo0[q]); pk[q+4] = f2bf(mo1[q]); }
        *(bf16x8*)&aggB[nl][2][f] = pk;
    }
    __syncthreads();

    // ---- Phase B: fully-unrolled barrier-free GEMM; wave w owns cols [w*32,+32) ----
    int wave = t >> 6, lane = t & 63;
    int lx = lane & 15, kb = lane >> 4;
    int n_lx = nb + lx;
    float famp = amp[n_lx], fatt = att[n_lx];
    const float* hsrc = curH + (size_t)n_lx * HD;
    const short* bbase = Wt + (size_t)(wave * 32 + lx) * 32 + kb * 8;
    f32x4 acc0 = {0.f,0.f,0.f,0.f}, acc1 = acc0;
    #pragma unroll
    for (int ks = 0; ks < 40; ++ks) {
        constexpr int KS4096 = 4096;
        int r = ks >> 2;                       // compile-time after unroll
        int kk = (ks & 3) * 32 + kb * 8;
        bf16x8 afrag;
        if (r < 9) {
            int ag = r % 3, fi = r / 3;
            bf16x8 raw = *(const bf16x8*)&aggB[lx][ag][kk];
            if (fi == 0) afrag = raw;
            else {
                float fac = (fi == 1) ? famp : fatt;
                #pragma unroll
                for (int q = 0; q < 8; ++q) afrag[q] = f2bf(bf2f(raw[q]) * fac);
            }
        } else {
            const float* src = hsrc + kk;
            float4 x0 = *(const float4*)src, x1 = *(const float4*)(src + 4);
            afrag[0]=f2bf(x0.x); afrag[1]=f2bf(x0.y); afrag[2]=f2bf(x0.z); afrag[3]=f2bf(x0.w);
            afrag[4]=f2bf(x1.x); afrag[5]=f2bf(x1.y); afrag[6]=f2bf(x1.z); afrag[7]=f2bf(x1.w);
        }
        const short* bp = bbase + (size_t)ks * KS4096;
        bf16x8 b0 = *(const bf16x8*)bp;
        bf16x8 b1 = *(const bf16x8*)(bp + 512);
        acc0 = __builtin_amdgcn_mfma_f32_16x16x32_bf16(afrag, b0, acc0, 0, 0, 0);
        acc1 = __builtin_amdgcn_mfma_f32_16x16x32_bf16(afrag, b1, acc1, 0, 0, 0);
    }
    #pragma unroll
    for (int jj = 0; jj < 2; ++jj) {
        int c = wave * 32 + jj * 16 + lx;
        float bc = bias[c];
        f32x4 av = jj ? acc1 : acc0;
        #pragma unroll
        for (int r_ = 0; r_ < 4; ++r_) {
            int n2 = nb + kb * 4 + r_;
            size_t off = (size_t)n2 * HD + c;
            float ho = av[r_] + bc + curH[off];
            nxtH[off] = ho;
            Ap2[n2 - nb][c] = f2bf(ho);
        }
    }
    if (nextWt != nullptr) {
        __syncthreads();
        // ---- Epilogue: next-layer projection; wave w owns 64 of 256 cols ----
        f32x4 acc[4];
        #pragma unroll
        for (int j = 0; j < 4; ++j) acc[j] = (f32x4){0.f, 0.f, 0.f, 0.f};
        #pragma unroll
        for (int ks = 0; ks < 4; ++ks) {
            bf16x8 aa = *(const bf16x8*)&Ap2[lx][ks * 32 + kb * 8];
            const short* bp = nextWt + (size_t)ks * 8192 + (size_t)(wave * 64 + lx) * 32 + kb * 8;
            #pragma unroll
            for (int jj = 0; jj < 4; ++jj) {
                bf16x8 bfr = *(const bf16x8*)(bp + jj * 512);
                acc[jj] = __builtin_amdgcn_mfma_f32_16x16x32_bf16(aa, bfr, acc[jj], 0, 0, 0);
            }
        }
        #pragma unroll
        for (int jj = 0; jj < 4; ++jj) {
            int c = wave * 64 + jj * 16 + lx;
            #pragma unroll
            for (int r_ = 0; r_ < 4; ++r_) {
                int n2 = nb + kb * 4 + r_;
                if (c < 128) hw0o[(size_t)n2 * HD + c] = f2bf(acc[jj][r_]);
                else         hw1o[(size_t)n2 * HD + (c - 128)] = acc[jj][r_];
            }
        }
    }
}

// Fused deterministic graph pooling + output MLP. One block per graph (batch sorted).
__global__ __launch_bounds__(256) void pool_out_kernel(
    const float* __restrict__ h, const int* __restrict__ batch,
    const float* __restrict__ W1, const float* __restrict__ b1,
    const float* __restrict__ W2, const float* __restrict__ b2,
    float* __restrict__ out)
{
    __shared__ float rs[384];
    __shared__ float red[256];
    __shared__ float s2[128], m2[128];
    int g = blockIdx.x, t = threadIdx.x;
    int lo = 0, hi = NN;
    while (lo < hi) { int mid = (lo + hi) >> 1; if (batch[mid] < g) lo = mid + 1; else hi = mid; }
    int lo2 = lo, hi2 = NN;
    while (lo2 < hi2) { int mid = (lo2 + hi2) >> 1; if (batch[mid] < g + 1) lo2 = mid + 1; else hi2 = mid; }
    int cnt = lo2 - lo;
    int f = t & 127, grp = t >> 7;
    float sum = 0.f, mx = -INFINITY;
    for (int n = lo + grp; n < lo2; n += 2) {
        float v = h[(size_t)n * HD + f];
        sum += v; mx = fmaxf(mx, v);
    }
    if (grp == 1) { s2[f] = sum; m2[f] = mx; }
    __syncthreads();
    if (grp == 0) {
        sum += s2[f]; mx = fmaxf(mx, m2[f]);
        float mean = (cnt > 0) ? sum / (float)cnt : 0.f;
        float so = (cnt > 0) ? sum : 0.f;
        float mo = (cnt > 0) ? mx : 0.f;
        if (isnan(mean) || isinf(mean)) mean = 0.f;
        if (isnan(so) || isinf(so)) so = 0.f;
        if (isnan(mo) || isinf(mo)) mo = 0.f;
        rs[f] = mean; rs[128 + f] = so; rs[256 + f] = mo;
    }
    __syncthreads();
    {
        int j = t & 127, kh = t >> 7;
        float acc = 0.f;
        for (int k = kh * 192; k < kh * 192 + 192; ++k)
            acc = fmaf(rs[k], W1[k * HD + j], acc);
        red[t] = acc;
    }
    __syncthreads();
    if (t < 128) {
        float v = fmaxf(red[t] + red[128 + t] + b1[t], 0.f);
        red[t] = v * W2[t];
    }
    __syncthreads();
    for (int s = 64; s > 0; s >>= 1) {
        if (t < s) red[t] += red[t + s];
        __syncthreads();
    }
    if (t == 0) {
        float o = red[0] + b2[0];
        if (isnan(o) || isinf(o)) o = 0.f;
        out[g] = o;
    }
}

extern "C" void kernel_launch(void* const* d_in, const int* in_sizes, int n_in,
                              void* d_out, int out_size, void* d_ws, size_t ws_size,
                              hipStream_t stream)
{
    const int* x          = (const int*)d_in[0];
    const int* ei         = (const int*)d_in[1];
    const int* ea         = (const int*)d_in[2];
    const int* batch      = (const int*)d_in[3];
    const float* atom_emb = (const float*)d_in[4];
    const float* bond_emb = (const float*)d_in[5];
    const float* pre_W    = (const float*)d_in[6];
    const float* pre_b    = (const float*)d_in[7];
    const float* post_W   = (const float*)d_in[8];
    const float* post_b   = (const float*)d_in[9];
    const float* out_W1   = (const float*)d_in[10];
    const float* out_b1   = (const float*)d_in[11];
    const float* out_W2   = (const float*)d_in[12];
    const float* out_b2   = (const float*)d_in[13];
    float* out = (float*)d_out;
    const int* row = ei;
    const int* col = ei + NE;

    char* p = (char*)d_ws;
    auto alloc = [&](size_t bytes) { char* r = p; p += (bytes + 255) & ~(size_t)255; return r; };
    float*    deg     = (float*)alloc((size_t)NN * 4);
    float*    amp     = (float*)alloc((size_t)NN * 4);
    float*    att     = (float*)alloc((size_t)NN * 4);
    int*      offsets = (int*)alloc((size_t)(NN + 1) * 4);
    int*      cursor  = (int*)alloc((size_t)NN * 4);
    int*      perm    = (int*)alloc((size_t)NE * 4);
    float*    hA      = (float*)alloc((size_t)NN * HD * 4);
    float*    hB      = (float*)alloc((size_t)NN * HD * 4);
    short*    hw0A    = (short*)alloc((size_t)NN * HD * 2);
    short*    hw0B    = (short*)alloc((size_t)NN * HD * 2);
    float*    hw1A    = (float*)alloc((size_t)NN * HD * 4);
    float*    hw1B    = (float*)alloc((size_t)NN * HD * 4);
    float*    btab    = (float*)alloc((size_t)NL * 5 * HD * 4);
    short*    pre_Wt  = (short*)alloc((size_t)NL * 4 * 256 * 32 * 2);
    short*    post_Wt = (short*)alloc((size_t)NL * 40 * 128 * 32 * 2);

    setup1_kernel<<<(NN * HD) / 256, 256, 0, stream>>>(x, atom_emb, hA, deg, cursor);
    setup2_kernel<<<645 + (NL * 40 * 128 * 32 + 255) / 256, 256, 0, stream>>>(
        col, deg, bond_emb, pre_W, pre_b, post_W, btab, pre_Wt, post_Wt);
    scan_facs_kernel<<<1, 1024, 0, stream>>>(deg, offsets, amp, att);
    scatter_kernel<<<(NE + 255) / 256, 256, 0, stream>>>(row, col, ea, offsets, cursor, perm);
    pre_gemm_kernel<<<NBLK, 256, 0, stream>>>(hA, pre_Wt, hw0A, hw1A);

    float* curH = hA;
    float* nxtH = hB;
    const short* hw0_in = hw0A;
    const float* hw1_in = hw1A;
    for (int l = 0; l < NL; ++l) {
        short* hw0_out = (l & 1) ? hw0A : hw0B;
        float* hw1_out = (l & 1) ? hw1A : hw1B;
        const short* nextWt = (l + 1 < NL) ? (pre_Wt + (size_t)(l + 1) * 32768) : nullptr;
        fused_kernel<<<NBLK, 256, 0, stream>>>(
            hw0_in, hw1_in, btab + (size_t)l * 5 * HD, offsets, perm,
            curH, amp, att, post_Wt + (size_t)l * 163840,
            post_b + (size_t)l * HD, nxtH, nextWt, hw0_out, hw1_out);
        float* tmp = curH; curH = nxtH; nxtH = tmp;
        hw0_in = hw0_out; hw1_in = hw1_out;
    }

    pool_out_kernel<<<NG, 256, 0, stream>>>(curH, batch, out_W1, out_b1, out_W2, out_b2, out);
}